// Round 4
// baseline (282.736 us; speedup 1.0000x reference)
//
#include <hip/hip_runtime.h>
#include <stdint.h>

// ---------------------------------------------------------------------------
// BertSelfAttention (relative_key_query) on gfx950.
// B=4 S=1024 H=768 nH=12 dH=64 MAXPOS=1024.
// R4: fix R3's E-staging race by loading E fragments directly from global
// into registers (L2-hot, compiler-managed vmcnt). LDS 52.75KB -> 3 blocks/CU.
// qkv: double-buffered pipeline + LDS-transpose epilogue (as R3).
// ---------------------------------------------------------------------------

typedef __attribute__((ext_vector_type(4))) float f32x4;
typedef __attribute__((ext_vector_type(8))) short s16x8;
typedef const __attribute__((address_space(1))) void GCV;
typedef __attribute__((address_space(3))) void LDSV;

__device__ __forceinline__ unsigned short f2bf(float f) {
  union { float f; uint32_t u; } v; v.f = f;
  uint32_t r = (v.u + 0x7FFFu + ((v.u >> 16) & 1u)) >> 16;
  return (unsigned short)r;
}
__device__ __forceinline__ float bf2f(unsigned short b) {
  union { uint32_t u; float f; } v; v.u = ((uint32_t)b) << 16;
  return v.f;
}
__device__ __forceinline__ uint32_t pack2(float a, float b) {
  return (uint32_t)f2bf(a) | ((uint32_t)f2bf(b) << 16);
}

#define MFMA(a, b, c) __builtin_amdgcn_mfma_f32_16x16x32_bf16((a), (b), (c), 0, 0, 0)

// ---------------------------------------------------------------------------
// Kernel 0: fp32 -> bf16 conversion.
// ---------------------------------------------------------------------------
#define HIDQ 786432   // 4096*768/4
#define WQ4  147456   // 768*768/4

__global__ __launch_bounds__(256) void convert_kernel(
    const float* __restrict__ hid, const float* __restrict__ wq,
    const float* __restrict__ wk, const float* __restrict__ wv,
    const float* __restrict__ de,
    unsigned short* __restrict__ hidbf, unsigned short* __restrict__ wbf,
    unsigned short* __restrict__ ebf) {
  int g = blockIdx.x * 256 + threadIdx.x;
  if (g < HIDQ) {
    float4 s = ((const float4*)hid)[g];
    ushort4 o; o.x = f2bf(s.x); o.y = f2bf(s.y); o.z = f2bf(s.z); o.w = f2bf(s.w);
    ((ushort4*)hidbf)[g] = o;
  } else if (g < HIDQ + 3 * WQ4) {
    int r = g - HIDQ;
    int sel = r / WQ4, r2 = r - sel * WQ4;
    const float* src = sel == 0 ? wq : (sel == 1 ? wk : wv);
    float4 s = ((const float4*)src)[r2];
    ushort4 o; o.x = f2bf(s.x); o.y = f2bf(s.y); o.z = f2bf(s.z); o.w = f2bf(s.w);
    ((ushort4*)wbf)[r] = o;
  } else {
    int r = g - HIDQ - 3 * WQ4;      // [0, 32768)
    int e = 4 * r;
    ushort4 o;
    o.x = (e + 0 < 131008) ? f2bf(de[e + 0]) : 0;
    o.y = (e + 1 < 131008) ? f2bf(de[e + 1]) : 0;
    o.z = (e + 2 < 131008) ? f2bf(de[e + 2]) : 0;
    o.w = (e + 3 < 131008) ? f2bf(de[e + 3]) : 0;
    ((ushort4*)ebf)[r] = o;
  }
}

// ---------------------------------------------------------------------------
// Kernel 1: QKV GEMM, double-buffered. C[m,o] = hid[m,:].W[o,:] + bias[o]
// M=4096, N=2304, K=768. 128x128 tile, BK=64, 1 barrier/iter (prefetch after
// barrier -> full iter to land). Epilogue: q/k via LDS transpose -> coalesced
// dwordx4 stores; v direct transposed stores.
// ---------------------------------------------------------------------------
__global__ __launch_bounds__(256, 2) void qkv_gemm(
    const unsigned short* __restrict__ hidbf,   // [4096][768]
    const unsigned short* __restrict__ wbf,     // [3][768][768]
    const float* __restrict__ bq, const float* __restrict__ bk,
    const float* __restrict__ bv,
    unsigned short* __restrict__ qb, unsigned short* __restrict__ kb,
    unsigned short* __restrict__ vtb) {
  __shared__ union {
    struct { unsigned short a[2][8192]; unsigned short b[2][8192]; } s;  // 64KB
    unsigned short cw[128 * 136];                                        // 34.8KB
  } sm;
  const int tid = threadIdx.x;
  const int w = tid >> 6, lane = tid & 63, quad = lane >> 4, l15 = lane & 15;
  const int m0 = blockIdx.x * 128;
  const int bn = blockIdx.y;
  const int sel = bn / 6;
  const int nc0 = (bn - sel * 6) * 128;
  const unsigned short* wsrc = wbf + (size_t)sel * 589824;

  f32x4 acc[4][4];
#pragma unroll
  for (int i = 0; i < 4; ++i)
#pragma unroll
    for (int j = 0; j < 4; ++j) acc[i][j] = (f32x4){0.f, 0.f, 0.f, 0.f};

  const int rA = 64 * (w & 1);
  const int rB = 64 * (w >> 1);
  int scl = w * 4;

  // prologue: stage kit=0 into buffer 0
#pragma unroll
  for (int i = 0; i < 4; ++i) {
    int cl = (scl + i) * 64 + lane;
    int row = cl >> 3, cp = cl & 7, gch = cp ^ (row & 7);
    __builtin_amdgcn_global_load_lds((GCV*)(hidbf + (size_t)(m0 + row) * 768 + gch * 8),
                                     (LDSV*)(sm.s.a[0] + (size_t)(scl + i) * 512), 16, 0, 0);
    __builtin_amdgcn_global_load_lds((GCV*)(wsrc + (size_t)(nc0 + row) * 768 + gch * 8),
                                     (LDSV*)(sm.s.b[0] + (size_t)(scl + i) * 512), 16, 0, 0);
  }

  for (int kit = 0; kit < 12; ++kit) {
    const int cur = kit & 1;
    __syncthreads();                       // drains staging issued last iter
    if (kit + 1 < 12) {                    // prefetch next tile
      int k0 = (kit + 1) * 64, nxt = cur ^ 1;
#pragma unroll
      for (int i = 0; i < 4; ++i) {
        int cl = (scl + i) * 64 + lane;
        int row = cl >> 3, cp = cl & 7, gch = cp ^ (row & 7);
        __builtin_amdgcn_global_load_lds(
            (GCV*)(hidbf + (size_t)(m0 + row) * 768 + k0 + gch * 8),
            (LDSV*)(sm.s.a[nxt] + (size_t)(scl + i) * 512), 16, 0, 0);
        __builtin_amdgcn_global_load_lds(
            (GCV*)(wsrc + (size_t)(nc0 + row) * 768 + k0 + gch * 8),
            (LDSV*)(sm.s.b[nxt] + (size_t)(scl + i) * 512), 16, 0, 0);
      }
    }
    s16x8 af[4][2], bfr[4][2];
#pragma unroll
    for (int mt = 0; mt < 4; ++mt)
#pragma unroll
      for (int ks = 0; ks < 2; ++ks) {
        int row = rA + 16 * mt + l15;
        af[mt][ks] = *(const s16x8*)(sm.s.a[cur] + row * 64 + (((quad + 4 * ks) ^ (row & 7)) * 8));
        int rowb = rB + 16 * mt + l15;
        bfr[mt][ks] = *(const s16x8*)(sm.s.b[cur] + rowb * 64 + (((quad + 4 * ks) ^ (rowb & 7)) * 8));
      }
#pragma unroll
    for (int mt = 0; mt < 4; ++mt)
#pragma unroll
      for (int nt = 0; nt < 4; ++nt) {
        acc[mt][nt] = MFMA(af[mt][0], bfr[nt][0], acc[mt][nt]);
        acc[mt][nt] = MFMA(af[mt][1], bfr[nt][1], acc[mt][nt]);
      }
  }
  __syncthreads();                         // before LDS reuse (cw aliases a/b)

  const float* bias = sel == 0 ? bq : (sel == 1 ? bk : bv);
  if (sel < 2) {
#pragma unroll
    for (int nt = 0; nt < 4; ++nt) {
      int ocl = rB + 16 * nt + l15;
      float bvl = bias[nc0 + ocl];
#pragma unroll
      for (int mt = 0; mt < 4; ++mt) {
        int ml = rA + 16 * mt + 4 * quad;
#pragma unroll
        for (int r = 0; r < 4; ++r)
          sm.cw[(ml + r) * 136 + ocl] = f2bf(acc[mt][nt][r] + bvl);
      }
    }
    __syncthreads();
    int sl = tid & 127, hd = tid >> 7;
    int m = m0 + sl, bb = m >> 10, s = m & 1023;
    int hh = (nc0 + hd * 64) >> 6;
    unsigned short* dst = (sel == 0 ? qb : kb) + (size_t)(bb * 12 + hh) * 65536 + (size_t)s * 64;
    const unsigned short* srcr = sm.cw + sl * 136 + hd * 64;
#pragma unroll
    for (int c = 0; c < 8; ++c)
      *(s16x8*)(dst + c * 8) = *(const s16x8*)(srcr + c * 8);
  } else {
#pragma unroll
    for (int nt = 0; nt < 4; ++nt) {
      int oc = nc0 + rB + 16 * nt + l15;
      float bvl = bias[oc];
      int h = oc >> 6, dd = oc & 63;
#pragma unroll
      for (int mt = 0; mt < 4; ++mt) {
        int mbase = m0 + rA + 16 * mt + quad * 4;
        int bb = mbase >> 10, s = mbase & 1023;
        ushort4 pk;
        pk.x = f2bf(acc[mt][nt][0] + bvl); pk.y = f2bf(acc[mt][nt][1] + bvl);
        pk.z = f2bf(acc[mt][nt][2] + bvl); pk.w = f2bf(acc[mt][nt][3] + bvl);
        *(ushort4*)(vtb + (size_t)(bb * 12 + h) * 65536 + (size_t)dd * 1024 + s) = pk;
      }
    }
  }
}

// ---------------------------------------------------------------------------
// Kernel 2: fused attention, R4.
// Block = (bh, 64 q-rows), wave w owns i-strip [16w,16w+16). St transposed
// (A=k,B=q): lane holds St[j=16mt+4quad+r][i'=l15]. E fragments loaded
// DIRECTLY from global into registers (L2-hot 256KB table; no LDS staging,
// no race). Bias stored unsheared:
//   keb[t 128][j 64] (stride 70)  = k[j].E[t]   -- vector u32 producer writes
//   qet[w][t' 80][i' 16] (str 18) = q[i].E[t']  -- vector u32 producer writes
// Consumers gather on the diagonal (bank-clean scalar u16). k double-buffered.
// 2 barriers/iter. LDS 52.75KB -> 3 blocks/CU (grid 768 = one full pass).
// ---------------------------------------------------------------------------
__global__ __launch_bounds__(256, 3) void attn_kernel(
    const unsigned short* __restrict__ qb, const unsigned short* __restrict__ kb,
    const unsigned short* __restrict__ vtb, const unsigned short* __restrict__ ebf,
    const float* __restrict__ mask, float* __restrict__ out) {
  __shared__ unsigned short ksw[2][64 * 64];     // 16KB dbuf
  __shared__ unsigned short vsw[64 * 64];        // 8KB
  __shared__ unsigned short keb[128 * 70];       // 17.5KB Ke[t][j]
  __shared__ unsigned short qet[4][80 * 18];     // 11.25KB Qe[t'][i'] / P (aliased)

  const int tid = threadIdx.x;
  const int w = tid >> 6, lane = tid & 63, quad = lane >> 4, l15 = lane & 15;
  const int blk = blockIdx.x;
  const int bh = blk >> 4;
  const int l0 = (blk & 15) << 6;
  const int b = bh / 12;
  const int h = bh - b * 12;

  const unsigned short* qrow = qb + (size_t)bh * 65536 + (size_t)(l0 + 16 * w + l15) * 64;
  s16x8 qf[2];
  qf[0] = *(const s16x8*)(qrow + quad * 8);
  qf[1] = *(const s16x8*)(qrow + 32 + quad * 8);

  f32x4 oacc[4];
#pragma unroll
  for (int i = 0; i < 4; ++i) oacc[i] = (f32x4){0.f, 0.f, 0.f, 0.f};
  float lsum = 0.f;
  const float SC1 = 0.18033688f;   // log2(e)/8
  const float SC2 = 1.44269504f;   // log2(e)

  const unsigned short* kbh = kb + (size_t)bh * 65536;
  const unsigned short* vbh = vtb + (size_t)bh * 65536;
  unsigned short* qetW = &qet[w][0];

  // Ke tile ownership: nibble (w) per tp; balanced 5 tiles/wave; valid tiles
  // have tt+mt in [3,7]; wave w covers tt = w+tp, tp in [0,4].
  const uint32_t KETv[5] = {0x0008, 0x008C, 0x6FF6, 0x3100, 0x1000};

  // prologue: stage k for it=0 into ksw[0]
#pragma unroll
  for (int i = 0; i < 2; ++i) {
    int cl = (w * 2 + i) * 64 + lane;
    int row = cl >> 3, cp = cl & 7, gch = cp ^ (row & 7);
    __builtin_amdgcn_global_load_lds((GCV*)(kbh + row * 64 + gch * 8),
                                     (LDSV*)(ksw[0] + (size_t)(w * 2 + i) * 512), 16, 0, 0);
  }

  for (int it = 0; it < 16; ++it) {
    const int r0 = it << 6;
    const int dbase = l0 - r0 + 960;   // global E row of block-local t=0
    __syncthreads();                   // drains last iter's staging/prefetch

    // ---- E fragments direct from global (registers; vmcnt-managed)
    s16x8 ef[5][2];
    {
      const unsigned short* ebase = ebf + (size_t)dbase * 64;
#pragma unroll
      for (int tp = 0; tp < 5; ++tp) {
        const unsigned short* er = ebase + (size_t)(16 * (w + tp) + l15) * 64;
        ef[tp][0] = *(const s16x8*)(er + quad * 8);
        ef[tp][1] = *(const s16x8*)(er + 32 + quad * 8);
      }
    }
    // ---- stage v (current iter; drained by mid barrier), k (next iter)
    {
      const unsigned short* vbase = vbh + r0;
#pragma unroll
      for (int i = 0; i < 2; ++i) {
        int cl = (w * 2 + i) * 64 + lane;
        int row = cl >> 3, cp = cl & 7, gch = cp ^ (row & 7);
        __builtin_amdgcn_global_load_lds((GCV*)(vbase + (size_t)row * 1024 + gch * 8),
                                         (LDSV*)(vsw + (size_t)(w * 2 + i) * 512), 16, 0, 0);
      }
    }
    if (it < 15) {
      const unsigned short* kbase = kbh + (size_t)(r0 + 64) * 64;
      unsigned short* kdst = ksw[(it + 1) & 1];
#pragma unroll
      for (int i = 0; i < 2; ++i) {
        int cl = (w * 2 + i) * 64 + lane;
        int row = cl >> 3, cp = cl & 7, gch = cp ^ (row & 7);
        __builtin_amdgcn_global_load_lds((GCV*)(kbase + row * 64 + gch * 8),
                                         (LDSV*)(kdst + (size_t)(w * 2 + i) * 512), 16, 0, 0);
      }
    }

    // ---- k A-frags from current (prefetched last iter) buffer
    const unsigned short* kcur = ksw[it & 1];
    s16x8 kf[4][2];
#pragma unroll
    for (int mt = 0; mt < 4; ++mt)
#pragma unroll
      for (int ks = 0; ks < 2; ++ks) {
        int row = 16 * mt + l15;
        kf[mt][ks] = *(const s16x8*)(kcur + row * 64 + (((quad + 4 * ks) ^ (row & 7)) * 8));
      }

    // ---- St[j][i'] = k . q
    f32x4 st[4];
#pragma unroll
    for (int mt = 0; mt < 4; ++mt) {
      f32x4 a = (f32x4){0.f, 0.f, 0.f, 0.f};
      a = MFMA(kf[mt][0], qf[0], a);
      a = MFMA(kf[mt][1], qf[1], a);
      st[mt] = a;
    }

    // ---- Qe tiles tp=0..4 -> qet[t'][i']; Ke per ownership table -> keb
#pragma unroll
    for (int tp = 0; tp < 5; ++tp) {
      f32x4 a = (f32x4){0.f, 0.f, 0.f, 0.f};
      a = MFMA(qf[0], ef[tp][0], a);
      a = MFMA(qf[1], ef[tp][1], a);
      {
        int e = (16 * tp + l15) * 18 + 4 * quad;
        *(uint32_t*)(qetW + e) = pack2(a[0], a[1]);
        *(uint32_t*)(qetW + e + 2) = pack2(a[2], a[3]);
      }
      uint32_t km = (KETv[tp] >> (w * 4)) & 15;
      int tpr = 16 * (w + tp) + l15;
#pragma unroll
      for (int mt = 0; mt < 4; ++mt) {
        if ((km >> mt) & 1) {
          f32x4 ka = (f32x4){0.f, 0.f, 0.f, 0.f};
          ka = MFMA(kf[mt][0], ef[tp][0], ka);
          ka = MFMA(kf[mt][1], ef[tp][1], ka);
          int e = tpr * 70 + 16 * mt + 4 * quad;
          *(uint32_t*)(keb + e) = pack2(ka[0], ka[1]);
          *(uint32_t*)(keb + e + 2) = pack2(ka[2], ka[3]);
        }
      }
    }
    __syncthreads();   // keb (cross-wave) ready; v staged; k prefetch drained

    // ---- softmax: diagonal gathers (bank-clean scalar), max-free exp
    const float* mrow = mask + b * 1024 + r0;
    float pv[4][4];
#pragma unroll
    for (int mt = 0; mt < 4; ++mt) {
      float4 m4 = *(const float4*)(mrow + 16 * mt + 4 * quad);
#pragma unroll
      for (int r = 0; r < 4; ++r) {
        int j = 16 * mt + 4 * quad + r;
        float qv = bf2f(qetW[(l15 - j + 63) * 18 + l15]);
        float kv = bf2f(keb[(16 * w + l15 - j + 63) * 70 + j]);
        float mk = (&m4.x)[r];
        float p = __builtin_amdgcn_exp2f((st[mt][r] + qv + kv) * SC1 + mk * SC2);
        pv[mt][r] = p;
        lsum += p;
      }
    }
    // ---- P -> per-wave LDS [i'=l15][j] stride 72 (aliases qet region)
#pragma unroll
    for (int mt = 0; mt < 4; ++mt) {
      int e = l15 * 72 + 16 * mt + 4 * quad;
      *(uint32_t*)(qetW + e) = pack2(pv[mt][0], pv[mt][1]);
      *(uint32_t*)(qetW + e + 2) = pack2(pv[mt][2], pv[mt][3]);
    }
    s16x8 pf0 = *(const s16x8*)(qetW + l15 * 72 + quad * 8);
    s16x8 pf1 = *(const s16x8*)(qetW + l15 * 72 + 32 + quad * 8);

    // ---- O += P @ V
#pragma unroll
    for (int dt = 0; dt < 4; ++dt) {
      int row = 16 * dt + l15;
      s16x8 vf0 = *(const s16x8*)(vsw + row * 64 + ((quad ^ (row & 7)) * 8));
      s16x8 vf1 = *(const s16x8*)(vsw + row * 64 + (((quad + 4) ^ (row & 7)) * 8));
      oacc[dt] = MFMA(pf0, vf0, oacc[dt]);
      oacc[dt] = MFMA(pf1, vf1, oacc[dt]);
    }
  }

  // ---- finalize
  lsum += __shfl_xor(lsum, 16, 64);
  lsum += __shfl_xor(lsum, 32, 64);
#pragma unroll
  for (int r = 0; r < 4; ++r) {
    float ls = __shfl(lsum, quad * 4 + r, 64);
    float rinv = 1.0f / ls;
    int l = l0 + 16 * w + quad * 4 + r;
    float* dst = out + ((size_t)(b * 1024 + l)) * 768 + h * 64;
#pragma unroll
    for (int dt = 0; dt < 4; ++dt) dst[16 * dt + l15] = oacc[dt][r] * rinv;
  }
}

// ---------------------------------------------------------------------------
extern "C" void kernel_launch(void* const* d_in, const int* in_sizes, int n_in,
                              void* d_out, int out_size, void* d_ws, size_t ws_size,
                              hipStream_t stream) {
  const float* hid  = (const float*)d_in[0];
  const float* mask = (const float*)d_in[1];
  const float* wq   = (const float*)d_in[2];
  const float* bq   = (const float*)d_in[3];
  const float* wk   = (const float*)d_in[4];
  const float* bk   = (const float*)d_in[5];
  const float* wv   = (const float*)d_in[6];
  const float* bv   = (const float*)d_in[7];
  const float* de   = (const float*)d_in[8];

  char* ws = (char*)d_ws;
  unsigned short* hidbf = (unsigned short*)(ws);                  // 6,291,456 B
  unsigned short* wbf   = (unsigned short*)(ws + 6291456);        // 3,538,944 B
  unsigned short* ebf   = (unsigned short*)(ws + 9830400);        //   262,144 B
  unsigned short* qb    = (unsigned short*)(ws + 10092544);       // 6,291,456 B
  unsigned short* kb    = (unsigned short*)(ws + 16384000);       // 6,291,456 B
  unsigned short* vtb   = (unsigned short*)(ws + 22675456);       // 6,291,456 B

  convert_kernel<<<4928, 256, 0, stream>>>(hid, wq, wk, wv, de, hidbf, wbf, ebf);
  qkv_gemm<<<dim3(32, 18), 256, 0, stream>>>(hidbf, wbf, bq, bk, bv, qb, kb, vtb);
  attn_kernel<<<768, 256, 0, stream>>>(qb, kb, vtb, ebf, mask, (float*)d_out);
}

// Round 5
// 237.211 us; speedup vs baseline: 1.1919x; 1.1919x over previous
//
#include <hip/hip_runtime.h>
#include <stdint.h>

// ---------------------------------------------------------------------------
// BertSelfAttention (relative_key_query) on gfx950.
// B=4 S=1024 H=768 nH=12 dH=64 MAXPOS=1024.
// R5: attn back to R1 base + 2-barrier pipeline (v phase-dbuf), rolling E
// window, sheared keb[i][j] (vector consumer reads), qet[t'][i] (vector
// producer writes), alias-safe P phase. launch_bounds(256,2): no register
// starvation (R4 lesson: tight bounds made compiler re-issue loads per use).
// ---------------------------------------------------------------------------

typedef __attribute__((ext_vector_type(4))) float f32x4;
typedef __attribute__((ext_vector_type(8))) short s16x8;
typedef const __attribute__((address_space(1))) void GCV;
typedef __attribute__((address_space(3))) void LDSV;

__device__ __forceinline__ unsigned short f2bf(float f) {
  union { float f; uint32_t u; } v; v.f = f;
  uint32_t r = (v.u + 0x7FFFu + ((v.u >> 16) & 1u)) >> 16;
  return (unsigned short)r;
}
__device__ __forceinline__ float bf2f(unsigned short b) {
  union { uint32_t u; float f; } v; v.u = ((uint32_t)b) << 16;
  return v.f;
}
__device__ __forceinline__ float bfhi(uint32_t u) {
  union { uint32_t u; float f; } v; v.u = u & 0xFFFF0000u; return v.f;
}
__device__ __forceinline__ float bflo(uint32_t u) {
  union { uint32_t u; float f; } v; v.u = u << 16; return v.f;
}
__device__ __forceinline__ uint32_t pack2(float a, float b) {
  return (uint32_t)f2bf(a) | ((uint32_t)f2bf(b) << 16);
}

#define MFMA(a, b, c) __builtin_amdgcn_mfma_f32_16x16x32_bf16((a), (b), (c), 0, 0, 0)

// ---------------------------------------------------------------------------
// Kernel 0: fp32 -> bf16 conversion.
// ---------------------------------------------------------------------------
#define HIDQ 786432   // 4096*768/4
#define WQ4  147456   // 768*768/4

__global__ __launch_bounds__(256) void convert_kernel(
    const float* __restrict__ hid, const float* __restrict__ wq,
    const float* __restrict__ wk, const float* __restrict__ wv,
    const float* __restrict__ de,
    unsigned short* __restrict__ hidbf, unsigned short* __restrict__ wbf,
    unsigned short* __restrict__ ebf) {
  int g = blockIdx.x * 256 + threadIdx.x;
  if (g < HIDQ) {
    float4 s = ((const float4*)hid)[g];
    ushort4 o; o.x = f2bf(s.x); o.y = f2bf(s.y); o.z = f2bf(s.z); o.w = f2bf(s.w);
    ((ushort4*)hidbf)[g] = o;
  } else if (g < HIDQ + 3 * WQ4) {
    int r = g - HIDQ;
    int sel = r / WQ4, r2 = r - sel * WQ4;
    const float* src = sel == 0 ? wq : (sel == 1 ? wk : wv);
    float4 s = ((const float4*)src)[r2];
    ushort4 o; o.x = f2bf(s.x); o.y = f2bf(s.y); o.z = f2bf(s.z); o.w = f2bf(s.w);
    ((ushort4*)wbf)[r] = o;
  } else {
    int r = g - HIDQ - 3 * WQ4;      // [0, 32768)
    int e = 4 * r;
    ushort4 o;
    o.x = (e + 0 < 131008) ? f2bf(de[e + 0]) : 0;
    o.y = (e + 1 < 131008) ? f2bf(de[e + 1]) : 0;
    o.z = (e + 2 < 131008) ? f2bf(de[e + 2]) : 0;
    o.w = (e + 3 < 131008) ? f2bf(de[e + 3]) : 0;
    ((ushort4*)ebf)[r] = o;
  }
}

// ---------------------------------------------------------------------------
// Kernel 1: QKV GEMM, double-buffered (R4, passed). 128x128 tile, BK=64.
// ---------------------------------------------------------------------------
__global__ __launch_bounds__(256, 2) void qkv_gemm(
    const unsigned short* __restrict__ hidbf,   // [4096][768]
    const unsigned short* __restrict__ wbf,     // [3][768][768]
    const float* __restrict__ bq, const float* __restrict__ bk,
    const float* __restrict__ bv,
    unsigned short* __restrict__ qb, unsigned short* __restrict__ kb,
    unsigned short* __restrict__ vtb) {
  __shared__ union {
    struct { unsigned short a[2][8192]; unsigned short b[2][8192]; } s;  // 64KB
    unsigned short cw[128 * 136];                                        // 34.8KB
  } sm;
  const int tid = threadIdx.x;
  const int w = tid >> 6, lane = tid & 63, quad = lane >> 4, l15 = lane & 15;
  const int m0 = blockIdx.x * 128;
  const int bn = blockIdx.y;
  const int sel = bn / 6;
  const int nc0 = (bn - sel * 6) * 128;
  const unsigned short* wsrc = wbf + (size_t)sel * 589824;

  f32x4 acc[4][4];
#pragma unroll
  for (int i = 0; i < 4; ++i)
#pragma unroll
    for (int j = 0; j < 4; ++j) acc[i][j] = (f32x4){0.f, 0.f, 0.f, 0.f};

  const int rA = 64 * (w & 1);
  const int rB = 64 * (w >> 1);
  int scl = w * 4;

#pragma unroll
  for (int i = 0; i < 4; ++i) {
    int cl = (scl + i) * 64 + lane;
    int row = cl >> 3, cp = cl & 7, gch = cp ^ (row & 7);
    __builtin_amdgcn_global_load_lds((GCV*)(hidbf + (size_t)(m0 + row) * 768 + gch * 8),
                                     (LDSV*)(sm.s.a[0] + (size_t)(scl + i) * 512), 16, 0, 0);
    __builtin_amdgcn_global_load_lds((GCV*)(wsrc + (size_t)(nc0 + row) * 768 + gch * 8),
                                     (LDSV*)(sm.s.b[0] + (size_t)(scl + i) * 512), 16, 0, 0);
  }

  for (int kit = 0; kit < 12; ++kit) {
    const int cur = kit & 1;
    __syncthreads();
    if (kit + 1 < 12) {
      int k0 = (kit + 1) * 64, nxt = cur ^ 1;
#pragma unroll
      for (int i = 0; i < 4; ++i) {
        int cl = (scl + i) * 64 + lane;
        int row = cl >> 3, cp = cl & 7, gch = cp ^ (row & 7);
        __builtin_amdgcn_global_load_lds(
            (GCV*)(hidbf + (size_t)(m0 + row) * 768 + k0 + gch * 8),
            (LDSV*)(sm.s.a[nxt] + (size_t)(scl + i) * 512), 16, 0, 0);
        __builtin_amdgcn_global_load_lds(
            (GCV*)(wsrc + (size_t)(nc0 + row) * 768 + k0 + gch * 8),
            (LDSV*)(sm.s.b[nxt] + (size_t)(scl + i) * 512), 16, 0, 0);
      }
    }
    s16x8 af[4][2], bfr[4][2];
#pragma unroll
    for (int mt = 0; mt < 4; ++mt)
#pragma unroll
      for (int ks = 0; ks < 2; ++ks) {
        int row = rA + 16 * mt + l15;
        af[mt][ks] = *(const s16x8*)(sm.s.a[cur] + row * 64 + (((quad + 4 * ks) ^ (row & 7)) * 8));
        int rowb = rB + 16 * mt + l15;
        bfr[mt][ks] = *(const s16x8*)(sm.s.b[cur] + rowb * 64 + (((quad + 4 * ks) ^ (rowb & 7)) * 8));
      }
#pragma unroll
    for (int mt = 0; mt < 4; ++mt)
#pragma unroll
      for (int nt = 0; nt < 4; ++nt) {
        acc[mt][nt] = MFMA(af[mt][0], bfr[nt][0], acc[mt][nt]);
        acc[mt][nt] = MFMA(af[mt][1], bfr[nt][1], acc[mt][nt]);
      }
  }
  __syncthreads();

  const float* bias = sel == 0 ? bq : (sel == 1 ? bk : bv);
  if (sel < 2) {
#pragma unroll
    for (int nt = 0; nt < 4; ++nt) {
      int ocl = rB + 16 * nt + l15;
      float bvl = bias[nc0 + ocl];
#pragma unroll
      for (int mt = 0; mt < 4; ++mt) {
        int ml = rA + 16 * mt + 4 * quad;
#pragma unroll
        for (int r = 0; r < 4; ++r)
          sm.cw[(ml + r) * 136 + ocl] = f2bf(acc[mt][nt][r] + bvl);
      }
    }
    __syncthreads();
    int sl = tid & 127, hd = tid >> 7;
    int m = m0 + sl, bb = m >> 10, s = m & 1023;
    int hh = (nc0 + hd * 64) >> 6;
    unsigned short* dst = (sel == 0 ? qb : kb) + (size_t)(bb * 12 + hh) * 65536 + (size_t)s * 64;
    const unsigned short* srcr = sm.cw + sl * 136 + hd * 64;
#pragma unroll
    for (int c = 0; c < 8; ++c)
      *(s16x8*)(dst + c * 8) = *(const s16x8*)(srcr + c * 8);
  } else {
#pragma unroll
    for (int nt = 0; nt < 4; ++nt) {
      int oc = nc0 + rB + 16 * nt + l15;
      float bvl = bias[oc];
      int h = oc >> 6, dd = oc & 63;
#pragma unroll
      for (int mt = 0; mt < 4; ++mt) {
        int mbase = m0 + rA + 16 * mt + quad * 4;
        int bb = mbase >> 10, s = mbase & 1023;
        ushort4 pk;
        pk.x = f2bf(acc[mt][nt][0] + bvl); pk.y = f2bf(acc[mt][nt][1] + bvl);
        pk.z = f2bf(acc[mt][nt][2] + bvl); pk.w = f2bf(acc[mt][nt][3] + bvl);
        *(ushort4*)(vtb + (size_t)(bb * 12 + h) * 65536 + (size_t)dd * 1024 + s) = pk;
      }
    }
  }
}

// ---------------------------------------------------------------------------
// Kernel 2: fused attention, R5. Block = (bh, 64 q-rows); wave w = i-strip
// [16w,16w+16). Per iter: [A] stage k/E(rolling window)/v(phase-dbuf) ->
// [barrier B] -> [C] St + Qe/Ke MFMAs from LDS, write qet/keb ->
// [barrier D] -> [E] softmax gathers + PV. 2 barriers/iter. Race audit:
//  - consumers after D touch only keb/qet/vsw[cur]; next iter's A writes only
//    ksw/esw/vsw[cur^1]; producer keb writes of i+1 are fenced by B(i+1).
//  - esw circular slots overwritten at A(i) were last read in C(i-1), which
//    all waves completed before D(i-1).
// Layouts: keb sheared [i 64][j 64] stride 70 (consumer uint2, bank-clean);
// qet per-wave [t' 80][i 16] stride 18 (producer u32 pairs; consumer scalar
// gather hits 16 distinct banks). P aliases qet, [i][j] stride 72, written
// only after all Qe gathers (R4's alias-safe ordering). LDS 60KB -> 2 blk/CU.
// ---------------------------------------------------------------------------
__global__ __launch_bounds__(256, 2) void attn_kernel(
    const unsigned short* __restrict__ qb, const unsigned short* __restrict__ kb,
    const unsigned short* __restrict__ vtb, const unsigned short* __restrict__ ebf,
    const float* __restrict__ mask, float* __restrict__ out) {
  __shared__ unsigned short ksw[64 * 64];        // 8KB
  __shared__ unsigned short vsw[2][64 * 64];     // 16KB phase-dbuf
  __shared__ unsigned short esw[128 * 64];       // 16KB rolling circular window
  __shared__ unsigned short keb[64 * 70];        // 8.75KB sheared Ke[i][j]
  __shared__ unsigned short qet[4][1440];        // 11.25KB per-wave Qe / P

  const int tid = threadIdx.x;
  const int w = tid >> 6, lane = tid & 63, quad = lane >> 4, l15 = lane & 15;
  const int blk = blockIdx.x;
  const int bh = blk >> 4;
  const int l0 = (blk & 15) << 6;
  const int b = bh / 12;
  const int h = bh - b * 12;

  const unsigned short* qrow = qb + (size_t)bh * 65536 + (size_t)(l0 + 16 * w + l15) * 64;
  s16x8 qf[2];
  qf[0] = *(const s16x8*)(qrow + quad * 8);
  qf[1] = *(const s16x8*)(qrow + 32 + quad * 8);

  f32x4 oacc[4];
#pragma unroll
  for (int i = 0; i < 4; ++i) oacc[i] = (f32x4){0.f, 0.f, 0.f, 0.f};
  float lsum = 0.f;
  const float SC1 = 0.18033688f;   // log2(e)/8
  const float SC2 = 1.44269504f;   // log2(e)

  const unsigned short* kbh = kb + (size_t)bh * 65536;
  const unsigned short* vbh = vtb + (size_t)bh * 65536;
  unsigned short* qetW = &qet[w][0];

  // Ke tile ownership (verified: covers exactly the 20 tiles tt+mt in [3,7],
  // 5 per wave, tt = w+tp with tp in [0,4]).
  const uint32_t KETv[5] = {0x0008, 0x008C, 0x6FF6, 0x3100, 0x1000};

  for (int it = 0; it < 16; ++it) {
    const int r0 = it << 6;
    const int dbase = l0 - r0 + 960;   // global E row of block-local t=0
    const int eoff = dbase & 127;      // 0 or 64

    // ---- phase A: stage k(it) -> ksw, E new rows -> esw, v(it) -> vsw[it&1]
    {
      const unsigned short* kbase = kbh + (size_t)r0 * 64;
#pragma unroll
      for (int i = 0; i < 2; ++i) {
        int cl = (w * 2 + i) * 64 + lane;
        int row = cl >> 3, cp = cl & 7, gch = cp ^ (row & 7);
        __builtin_amdgcn_global_load_lds((GCV*)(kbase + row * 64 + gch * 8),
                                         (LDSV*)(ksw + (size_t)(w * 2 + i) * 512), 16, 0, 0);
      }
      const unsigned short* vbase = vbh + r0;
      unsigned short* vdst = vsw[it & 1];
#pragma unroll
      for (int i = 0; i < 2; ++i) {
        int cl = (w * 2 + i) * 64 + lane;
        int row = cl >> 3, cp = cl & 7, gch = cp ^ (row & 7);
        __builtin_amdgcn_global_load_lds((GCV*)(vbase + (size_t)row * 1024 + gch * 8),
                                         (LDSV*)(vdst + (size_t)(w * 2 + i) * 512), 16, 0, 0);
      }
      if (it == 0) {
#pragma unroll
        for (int i = 0; i < 4; ++i) {
          int row0 = (w * 4 + i) * 8;
          int row = row0 + (lane >> 3), cp = lane & 7, gch = cp ^ (row & 7);
          int lbase = ((eoff + row0) & 127) * 64;
          __builtin_amdgcn_global_load_lds((GCV*)(ebf + (size_t)(dbase + row) * 64 + gch * 8),
                                           (LDSV*)(esw + lbase), 16, 0, 0);
        }
      } else {
#pragma unroll
        for (int i = 0; i < 2; ++i) {
          int row0 = (w * 2 + i) * 8;                 // new rows [0,64)
          int row = row0 + (lane >> 3), cp = lane & 7, gch = cp ^ (row & 7);
          int lbase = ((eoff + row0) & 127) * 64;
          __builtin_amdgcn_global_load_lds((GCV*)(ebf + (size_t)(dbase + row) * 64 + gch * 8),
                                           (LDSV*)(esw + lbase), 16, 0, 0);
        }
      }
    }
    __syncthreads();   // barrier B: all staging drained

    // ---- phase C: k frags, St, Qe/Ke producers
    s16x8 kf[4][2];
#pragma unroll
    for (int mt = 0; mt < 4; ++mt)
#pragma unroll
      for (int ks = 0; ks < 2; ++ks) {
        int row = 16 * mt + l15;
        kf[mt][ks] = *(const s16x8*)(ksw + row * 64 + (((quad + 4 * ks) ^ (row & 7)) * 8));
      }

    f32x4 st[4];
#pragma unroll
    for (int mt = 0; mt < 4; ++mt) {
      f32x4 a = (f32x4){0.f, 0.f, 0.f, 0.f};
      a = MFMA(kf[mt][0], qf[0], a);
      a = MFMA(kf[mt][1], qf[1], a);
      st[mt] = a;
    }

#pragma unroll
    for (int tp = 0; tp < 5; ++tp) {
      int tpr = 16 * (w + tp) + l15;            // block-local t
      int erow = (eoff + tpr) & 127;
      int sw = erow & 7;
      s16x8 ef0 = *(const s16x8*)(esw + erow * 64 + ((quad ^ sw) * 8));
      s16x8 ef1 = *(const s16x8*)(esw + erow * 64 + (((quad + 4) ^ sw) * 8));
      f32x4 a = (f32x4){0.f, 0.f, 0.f, 0.f};
      a = MFMA(qf[0], ef0, a);
      a = MFMA(qf[1], ef1, a);
      {  // Qe[t'loc = 16tp+l15][i' = 4quad+r], stride 18, u32 pairs
        int e = (16 * tp + l15) * 18 + 4 * quad;
        *(uint32_t*)(qetW + e) = pack2(a[0], a[1]);
        *(uint32_t*)(qetW + e + 2) = pack2(a[2], a[3]);
      }
      uint32_t km = (KETv[tp] >> (w * 4)) & 15;
#pragma unroll
      for (int mt = 0; mt < 4; ++mt) {
        if ((km >> mt) & 1) {
          f32x4 ka = (f32x4){0.f, 0.f, 0.f, 0.f};
          ka = MFMA(kf[mt][0], ef0, ka);
          ka = MFMA(kf[mt][1], ef1, ka);
          int s = w + tp + mt;                  // tile diagonal class in [3,7]
          int jb = 16 * mt + 4 * quad;
          int ibb = tpr + jb - 63;              // sheared row for r=0
#pragma unroll
          for (int r = 0; r < 4; ++r) {
            int ib = ibb + r, j = jb + r;
            if (s == 3)      { if (ib >= 0) keb[ib * 70 + j] = f2bf(ka[r]); }
            else if (s == 7) { if (ib < 64) keb[ib * 70 + j] = f2bf(ka[r]); }
            else keb[ib * 70 + j] = f2bf(ka[r]);
          }
        }
      }
    }
    __syncthreads();   // barrier D: keb/qet ready

    // ---- phase E: softmax (gather all, then write P), PV
    const float* mrow = mask + b * 1024 + r0;
    float pv4[4][4];
#pragma unroll
    for (int mt = 0; mt < 4; ++mt) {
      uint2 kv = *(const uint2*)(keb + (16 * w + l15) * 70 + 16 * mt + 4 * quad);
      float4 m4 = *(const float4*)(mrow + 16 * mt + 4 * quad);
      float kvf[4] = {bflo(kv.x), bfhi(kv.x), bflo(kv.y), bfhi(kv.y)};
#pragma unroll
      for (int r = 0; r < 4; ++r) {
        int j = 16 * mt + 4 * quad + r;
        float qv = bf2f(qetW[(l15 - j + 63) * 18 + l15]);
        float p = __builtin_amdgcn_exp2f((st[mt][r] + qv + kvf[r]) * SC1 + (&m4.x)[r] * SC2);
        pv4[mt][r] = p;
        lsum += p;
      }
    }
#pragma unroll
    for (int mt = 0; mt < 4; ++mt) {   // P[i'=l15][j] stride 72 (aliases qet)
      int e = l15 * 72 + 16 * mt + 4 * quad;
      *(uint32_t*)(qetW + e) = pack2(pv4[mt][0], pv4[mt][1]);
      *(uint32_t*)(qetW + e + 2) = pack2(pv4[mt][2], pv4[mt][3]);
    }
    s16x8 pf0 = *(const s16x8*)(qetW + l15 * 72 + quad * 8);
    s16x8 pf1 = *(const s16x8*)(qetW + l15 * 72 + 32 + quad * 8);

    const unsigned short* vcur = vsw[it & 1];
#pragma unroll
    for (int dt = 0; dt < 4; ++dt) {
      int row = 16 * dt + l15;
      s16x8 vf0 = *(const s16x8*)(vcur + row * 64 + ((quad ^ (row & 7)) * 8));
      s16x8 vf1 = *(const s16x8*)(vcur + row * 64 + (((quad + 4) ^ (row & 7)) * 8));
      oacc[dt] = MFMA(pf0, vf0, oacc[dt]);
      oacc[dt] = MFMA(pf1, vf1, oacc[dt]);
    }
  }

  // ---- finalize
  lsum += __shfl_xor(lsum, 16, 64);
  lsum += __shfl_xor(lsum, 32, 64);
#pragma unroll
  for (int r = 0; r < 4; ++r) {
    float ls = __shfl(lsum, quad * 4 + r, 64);
    float rinv = 1.0f / ls;
    int l = l0 + 16 * w + quad * 4 + r;
    float* dst = out + ((size_t)(b * 1024 + l)) * 768 + h * 64;
#pragma unroll
    for (int dt = 0; dt < 4; ++dt) dst[16 * dt + l15] = oacc[dt][r] * rinv;
  }
}

// ---------------------------------------------------------------------------
extern "C" void kernel_launch(void* const* d_in, const int* in_sizes, int n_in,
                              void* d_out, int out_size, void* d_ws, size_t ws_size,
                              hipStream_t stream) {
  const float* hid  = (const float*)d_in[0];
  const float* mask = (const float*)d_in[1];
  const float* wq   = (const float*)d_in[2];
  const float* bq   = (const float*)d_in[3];
  const float* wk   = (const float*)d_in[4];
  const float* bk   = (const float*)d_in[5];
  const float* wv   = (const float*)d_in[6];
  const float* bv   = (const float*)d_in[7];
  const float* de   = (const float*)d_in[8];

  char* ws = (char*)d_ws;
  unsigned short* hidbf = (unsigned short*)(ws);                  // 6,291,456 B
  unsigned short* wbf   = (unsigned short*)(ws + 6291456);        // 3,538,944 B
  unsigned short* ebf   = (unsigned short*)(ws + 9830400);        //   262,144 B
  unsigned short* qb    = (unsigned short*)(ws + 10092544);       // 6,291,456 B
  unsigned short* kb    = (unsigned short*)(ws + 16384000);       // 6,291,456 B
  unsigned short* vtb   = (unsigned short*)(ws + 22675456);       // 6,291,456 B

  convert_kernel<<<4928, 256, 0, stream>>>(hid, wq, wk, wv, de, hidbf, wbf, ebf);
  qkv_gemm<<<dim3(32, 18), 256, 0, stream>>>(hidbf, wbf, bq, bk, bv, qb, kb, vtb);
  attn_kernel<<<768, 256, 0, stream>>>(qb, kb, vtb, ebf, mask, (float*)d_out);
}